// Round 3
// baseline (1092.498 us; speedup 1.0000x reference)
//
#include <hip/hip_runtime.h>
#include <math.h>

#define B 256
#define N 1152
#define C_ 10
#define OUT 16
#define IN 8
#define KO 160          // C_*OUT
#define MB 16           // batch tile for s-partial
#define NC 32           // n-chunk for s-partial
#define NCH 36          // N / NC
#define KG 2            // capsules per k-group (5 groups)
#define NKG 5
#define XS_STRIDE (NC*IN + 8)   // 264: rows land 8 banks apart -> conflict-free

// ---------------- s-partial: partial[ch][b][k*16+o] = sum_{n in chunk} c[n,k] * (W[n,k,o,:] . x[b,n,:])
// grid (16, 36, 5): batch-tile, n-chunk, k-group
__global__ __launch_bounds__(256, 8) void k_s_partial(
    const float* __restrict__ x, const float* __restrict__ W,
    const float* __restrict__ c, float* __restrict__ partial)
{
    __shared__ float xs[MB][XS_STRIDE];   // 16 x 264 floats = 16.9 KB
    __shared__ float cs[NC][KG];

    const int tid = threadIdx.x;
    const int bt  = blockIdx.x;   // 0..15
    const int ch  = blockIdx.y;   // 0..35
    const int kg  = blockIdx.z;   // 0..4
    const int b0  = bt * MB;
    const int n0  = ch * NC;
    const int k0  = kg * KG;

    // load x tile: row = 256 contiguous floats = 64 float4
    for (int idx = tid; idx < MB * NC * IN / 4; idx += 256) {
        int bl = idx >> 6;
        int r  = idx & 63;
        float4 val = *(const float4*)(x + (size_t)(b0 + bl) * (N * IN) + (size_t)n0 * IN + r * 4);
        *(float4*)(&xs[bl][r * 4]) = val;
    }
    if (c) {
        for (int idx = tid; idx < NC * KG; idx += 256) {
            int nl = idx / KG, kk = idx % KG;
            cs[nl][kk] = c[(size_t)(n0 + nl) * C_ + (k0 + kk)];
        }
    }
    __syncthreads();

    const int o  = tid & 15;
    const int bl = tid >> 4;

    float acc[KG];
#pragma unroll
    for (int kk = 0; kk < KG; ++kk) acc[kk] = 0.f;

    const float* Wbase = W + (size_t)n0 * (KO * IN) + (size_t)(k0 * OUT + o) * IN;

#pragma unroll 4
    for (int nl = 0; nl < NC; ++nl) {
        float xv[IN];
#pragma unroll
        for (int i = 0; i < IN; ++i) xv[i] = xs[bl][nl * IN + i];
        const float* Wn = Wbase + (size_t)nl * (KO * IN);
#pragma unroll
        for (int kk = 0; kk < KG; ++kk) {
            const float4* wp = (const float4*)(Wn + kk * (OUT * IN));
            float4 w0 = wp[0], w1 = wp[1];
            float d = w0.x * xv[0] + w0.y * xv[1] + w0.z * xv[2] + w0.w * xv[3]
                    + w1.x * xv[4] + w1.y * xv[5] + w1.z * xv[6] + w1.w * xv[7];
            float cw = c ? cs[nl][kk] : 0.1f;   // it0: softmax(0) = 1/C exactly
            acc[kk] += cw * d;
        }
    }

    float* pp = partial + (size_t)ch * (B * KO) + (size_t)(b0 + bl) * KO + (size_t)k0 * OUT + o;
#pragma unroll
    for (int kk = 0; kk < KG; ++kk) pp[kk * OUT] = acc[kk];
}

// ---------------- reduce partials over chunks + squash; 4 threads per element
// grid 640 blocks x 256: block handles 64 elements
__global__ __launch_bounds__(256) void k_reduce_squash(
    const float* __restrict__ partial, float* __restrict__ v, float* __restrict__ out)
{
    __shared__ float red[256];
    const int tid = threadIdx.x;
    const int e   = blockIdx.x * 64 + (tid >> 2);   // element 0..40959
    const int q   = tid & 3;                        // quarter: 9 chunks each
    float s = 0.f;
#pragma unroll
    for (int ch = 0; ch < NCH / 4; ++ch)
        s += partial[(size_t)(q * (NCH / 4) + ch) * (B * KO) + e];
    red[tid] = s;
    __syncthreads();
    if (q == 0) {
        s = red[tid] + red[tid + 1] + red[tid + 2] + red[tid + 3];
        float vv = s * fabsf(s) / (1.f + s * s);
        v[e] = vv;
        if (out) out[e] = vv;
    }
}

// ---------------- a-pass: b_ij[n][k] (+)= (1/B) sum_{b,o} (W[n,k,o,:].x[b,n,:]) * v[b,k,o]
__global__ __launch_bounds__(256) void k_a(
    const float* __restrict__ x, const float* __restrict__ W,
    const float* __restrict__ v, float* __restrict__ bij, int accumulate)
{
    const int n = blockIdx.x;
    const int tid = threadIdx.x;

    __shared__ float Wl[KO][IN + 1];   // padded: stride 9 -> conflict-free
    __shared__ float xsl[B][IN];       // 8 KB
    __shared__ float red[256][C_];     // 10 KB

    for (int idx = tid; idx < KO * IN; idx += 256)
        Wl[idx >> 3][idx & 7] = W[(size_t)n * (KO * IN) + idx];
    for (int idx = tid; idx < B * IN / 4; idx += 256) {   // 512 float4
        int bb = idx >> 1, r = idx & 1;
        *(float4*)(&xsl[bb][r * 4]) = *(const float4*)(x + (size_t)bb * (N * IN) + (size_t)n * IN + r * 4);
    }
    __syncthreads();

    const int o = tid & 15;
    const int blane = tid >> 4;

    float part[C_];
#pragma unroll
    for (int k = 0; k < C_; ++k) part[k] = 0.f;

    for (int t = 0; t < B / 16; ++t) {
        int bb = blane + t * 16;
        float xv[IN];
#pragma unroll
        for (int i = 0; i < IN; ++i) xv[i] = xsl[bb][i];
        const float* vb = v + (size_t)bb * KO + o;
#pragma unroll
        for (int k = 0; k < C_; ++k) {
            const float* wp = &Wl[k * OUT + o][0];
            float d = 0.f;
#pragma unroll
            for (int i = 0; i < IN; ++i) d += wp[i] * xv[i];
            part[k] += d * vb[k * OUT];
        }
    }

#pragma unroll
    for (int k = 0; k < C_; ++k) red[tid][k] = part[k];
    __syncthreads();
    for (int off = 128; off > 0; off >>= 1) {
        if (tid < off) {
#pragma unroll
            for (int k = 0; k < C_; ++k) red[tid][k] += red[tid + off][k];
        }
        __syncthreads();
    }
    if (tid < C_) {
        float a = red[0][tid] * (1.0f / B);
        float* bp = bij + (size_t)n * C_ + tid;
        *bp = accumulate ? (*bp + a) : a;
    }
}

// ---------------- softmax over k (10) per n
__global__ __launch_bounds__(256) void k_softmax(
    const float* __restrict__ bij, float* __restrict__ c)
{
    int n = blockIdx.x * 256 + threadIdx.x;
    if (n >= N) return;
    float b[C_], m = -1e30f;
#pragma unroll
    for (int k = 0; k < C_; ++k) { b[k] = bij[(size_t)n * C_ + k]; m = fmaxf(m, b[k]); }
    float s = 0.f;
#pragma unroll
    for (int k = 0; k < C_; ++k) { float e = __expf(b[k] - m); b[k] = e; s += e; }
    float inv = 1.f / s;
#pragma unroll
    for (int k = 0; k < C_; ++k) c[(size_t)n * C_ + k] = b[k] * inv;
}

extern "C" void kernel_launch(void* const* d_in, const int* in_sizes, int n_in,
                              void* d_out, int out_size, void* d_ws, size_t ws_size,
                              hipStream_t stream)
{
    const float* x = (const float*)d_in[0];   // [B, N, IN]
    const float* W = (const float*)d_in[1];   // [1, N, C, OUT, IN]
    float* out = (float*)d_out;               // [B, C, OUT, 1] = 40960 floats
    float* ws  = (float*)d_ws;

    float* part = ws;                         // 36 * 40960 = 1474560 floats (5.9 MB)
    float* bij  = ws + 1474560;               // 11520
    float* c    = bij + 11520;                // 11520
    float* v    = c + 11520;                  // 40960

    dim3 gS(16, NCH, NKG);

    // iteration 0: c = 1/C exactly (softmax of zeros); b_ij = a  (write mode, no init needed)
    k_s_partial<<<gS, 256, 0, stream>>>(x, W, nullptr, part);
    k_reduce_squash<<<640, 256, 0, stream>>>(part, v, nullptr);
    k_a<<<N, 256, 0, stream>>>(x, W, v, bij, 0);

    // iteration 1
    k_softmax<<<5, 256, 0, stream>>>(bij, c);
    k_s_partial<<<gS, 256, 0, stream>>>(x, W, c, part);
    k_reduce_squash<<<640, 256, 0, stream>>>(part, v, nullptr);
    k_a<<<N, 256, 0, stream>>>(x, W, v, bij, 1);

    // iteration 2 (final: write d_out)
    k_softmax<<<5, 256, 0, stream>>>(bij, c);
    k_s_partial<<<gS, 256, 0, stream>>>(x, W, c, part);
    k_reduce_squash<<<640, 256, 0, stream>>>(part, v, out);
}

// Round 4
// 199.212 us; speedup vs baseline: 5.4841x; 5.4841x over previous
//
#include <hip/hip_runtime.h>
#include <math.h>

#define B 256
#define N 1152
#define C_ 10
#define OUT 16
#define IN 8
#define KO 160          // C_*OUT
#define MB 16           // batch tile for s-partial
#define NC 32           // n-chunk for s-partial
#define NCH 36          // N / NC
#define KG 2            // capsules per k-group (5 groups)
#define NKG 5
#define XS_STRIDE (NC*IN + 8)   // 264: rows land 8 banks apart -> conflict-free

// ---------------- s-partial: partial[ch][b][k*16+o] = sum_{n in chunk} c[n,k] * (W[n,k,o,:] . x[b,n,:])
// grid (16, 36, 5): batch-tile, n-chunk, k-group
// NOTE: launch_bounds min-waves deliberately 4, NOT 8 — (256,8) forced VGPR=32 and
// spilled every inner-loop temp to scratch (R3: 1.7 GB HBM traffic/dispatch, 5x slower).
__global__ __launch_bounds__(256, 4) void k_s_partial(
    const float* __restrict__ x, const float* __restrict__ W,
    const float* __restrict__ c, float* __restrict__ partial)
{
    __shared__ float xs[MB][XS_STRIDE];   // 16 x 264 floats = 16.9 KB
    __shared__ float cs[NC][KG];

    const int tid = threadIdx.x;
    const int bt  = blockIdx.x;   // 0..15
    const int ch  = blockIdx.y;   // 0..35
    const int kg  = blockIdx.z;   // 0..4
    const int b0  = bt * MB;
    const int n0  = ch * NC;
    const int k0  = kg * KG;

    // load x tile: row = 256 contiguous floats = 64 float4
    for (int idx = tid; idx < MB * NC * IN / 4; idx += 256) {
        int bl = idx >> 6;
        int r  = idx & 63;
        float4 val = *(const float4*)(x + (size_t)(b0 + bl) * (N * IN) + (size_t)n0 * IN + r * 4);
        *(float4*)(&xs[bl][r * 4]) = val;
    }
    if (c) {
        for (int idx = tid; idx < NC * KG; idx += 256) {
            int nl = idx / KG, kk = idx % KG;
            cs[nl][kk] = c[(size_t)(n0 + nl) * C_ + (k0 + kk)];
        }
    }
    __syncthreads();

    const int o  = tid & 15;
    const int bl = tid >> 4;

    float acc[KG];
#pragma unroll
    for (int kk = 0; kk < KG; ++kk) acc[kk] = 0.f;

    const float* Wbase = W + (size_t)n0 * (KO * IN) + (size_t)(k0 * OUT + o) * IN;

#pragma unroll 2
    for (int nl = 0; nl < NC; ++nl) {
        // vectorized LDS read: 2x ds_read_b128, 16B-aligned, broadcast within 16-lane groups
        float4 x0 = *(const float4*)(&xs[bl][nl * IN]);
        float4 x1 = *(const float4*)(&xs[bl][nl * IN + 4]);
        const float* Wn = Wbase + (size_t)nl * (KO * IN);
#pragma unroll
        for (int kk = 0; kk < KG; ++kk) {
            const float4* wp = (const float4*)(Wn + kk * (OUT * IN));
            float4 w0 = wp[0], w1 = wp[1];
            float d = w0.x * x0.x + w0.y * x0.y + w0.z * x0.z + w0.w * x0.w
                    + w1.x * x1.x + w1.y * x1.y + w1.z * x1.z + w1.w * x1.w;
            float cw = c ? cs[nl][kk] : 0.1f;   // it0: softmax(0) = 1/C exactly
            acc[kk] += cw * d;
        }
    }

    float* pp = partial + (size_t)ch * (B * KO) + (size_t)(b0 + bl) * KO + (size_t)k0 * OUT + o;
#pragma unroll
    for (int kk = 0; kk < KG; ++kk) pp[kk * OUT] = acc[kk];
}

// ---------------- reduce partials over chunks + squash; 4 threads per element
// grid 640 blocks x 256: block handles 64 elements
__global__ __launch_bounds__(256) void k_reduce_squash(
    const float* __restrict__ partial, float* __restrict__ v, float* __restrict__ out)
{
    __shared__ float red[256];
    const int tid = threadIdx.x;
    const int e   = blockIdx.x * 64 + (tid >> 2);   // element 0..40959
    const int q   = tid & 3;                        // quarter: 9 chunks each
    float s = 0.f;
#pragma unroll
    for (int ch = 0; ch < NCH / 4; ++ch)
        s += partial[(size_t)(q * (NCH / 4) + ch) * (B * KO) + e];
    red[tid] = s;
    __syncthreads();
    if (q == 0) {
        s = red[tid] + red[tid + 1] + red[tid + 2] + red[tid + 3];
        float vv = s * fabsf(s) / (1.f + s * s);
        v[e] = vv;
        if (out) out[e] = vv;
    }
}

// ---------------- a-pass: b_ij[n][k] (+)= (1/B) sum_{b,o} (W[n,k,o,:].x[b,n,:]) * v[b,k,o]
__global__ __launch_bounds__(256) void k_a(
    const float* __restrict__ x, const float* __restrict__ W,
    const float* __restrict__ v, float* __restrict__ bij, int accumulate)
{
    const int n = blockIdx.x;
    const int tid = threadIdx.x;

    __shared__ float Wl[KO][IN + 1];   // padded: stride 9 -> conflict-free
    __shared__ float xsl[B][IN];       // 8 KB
    __shared__ float red[256][C_];     // 10 KB

    for (int idx = tid; idx < KO * IN; idx += 256)
        Wl[idx >> 3][idx & 7] = W[(size_t)n * (KO * IN) + idx];
    for (int idx = tid; idx < B * IN / 4; idx += 256) {   // 512 float4
        int bb = idx >> 1, r = idx & 1;
        *(float4*)(&xsl[bb][r * 4]) = *(const float4*)(x + (size_t)bb * (N * IN) + (size_t)n * IN + r * 4);
    }
    __syncthreads();

    const int o = tid & 15;
    const int blane = tid >> 4;

    float part[C_];
#pragma unroll
    for (int k = 0; k < C_; ++k) part[k] = 0.f;

    for (int t = 0; t < B / 16; ++t) {
        int bb = blane + t * 16;
        float xv[IN];
#pragma unroll
        for (int i = 0; i < IN; ++i) xv[i] = xsl[bb][i];
        const float* vb = v + (size_t)bb * KO + o;
#pragma unroll
        for (int k = 0; k < C_; ++k) {
            const float* wp = &Wl[k * OUT + o][0];
            float d = 0.f;
#pragma unroll
            for (int i = 0; i < IN; ++i) d += wp[i] * xv[i];
            part[k] += d * vb[k * OUT];
        }
    }

#pragma unroll
    for (int k = 0; k < C_; ++k) red[tid][k] = part[k];
    __syncthreads();
    for (int off = 128; off > 0; off >>= 1) {
        if (tid < off) {
#pragma unroll
            for (int k = 0; k < C_; ++k) red[tid][k] += red[tid + off][k];
        }
        __syncthreads();
    }
    if (tid < C_) {
        float a = red[0][tid] * (1.0f / B);
        float* bp = bij + (size_t)n * C_ + tid;
        *bp = accumulate ? (*bp + a) : a;
    }
}

// ---------------- softmax over k (10) per n
__global__ __launch_bounds__(256) void k_softmax(
    const float* __restrict__ bij, float* __restrict__ c)
{
    int n = blockIdx.x * 256 + threadIdx.x;
    if (n >= N) return;
    float b[C_], m = -1e30f;
#pragma unroll
    for (int k = 0; k < C_; ++k) { b[k] = bij[(size_t)n * C_ + k]; m = fmaxf(m, b[k]); }
    float s = 0.f;
#pragma unroll
    for (int k = 0; k < C_; ++k) { float e = __expf(b[k] - m); b[k] = e; s += e; }
    float inv = 1.f / s;
#pragma unroll
    for (int k = 0; k < C_; ++k) c[(size_t)n * C_ + k] = b[k] * inv;
}

extern "C" void kernel_launch(void* const* d_in, const int* in_sizes, int n_in,
                              void* d_out, int out_size, void* d_ws, size_t ws_size,
                              hipStream_t stream)
{
    const float* x = (const float*)d_in[0];   // [B, N, IN]
    const float* W = (const float*)d_in[1];   // [1, N, C, OUT, IN]
    float* out = (float*)d_out;               // [B, C, OUT, 1] = 40960 floats
    float* ws  = (float*)d_ws;

    float* part = ws;                         // 36 * 40960 = 1474560 floats (5.9 MB)
    float* bij  = ws + 1474560;               // 11520
    float* c    = bij + 11520;                // 11520
    float* v    = c + 11520;                  // 40960

    dim3 gS(16, NCH, NKG);

    // iteration 0: c = 1/C exactly (softmax of zeros); b_ij = a  (write mode, no init needed)
    k_s_partial<<<gS, 256, 0, stream>>>(x, W, nullptr, part);
    k_reduce_squash<<<640, 256, 0, stream>>>(part, v, nullptr);
    k_a<<<N, 256, 0, stream>>>(x, W, v, bij, 0);

    // iteration 1
    k_softmax<<<5, 256, 0, stream>>>(bij, c);
    k_s_partial<<<gS, 256, 0, stream>>>(x, W, c, part);
    k_reduce_squash<<<640, 256, 0, stream>>>(part, v, nullptr);
    k_a<<<N, 256, 0, stream>>>(x, W, v, bij, 1);

    // iteration 2 (final: write d_out)
    k_softmax<<<5, 256, 0, stream>>>(bij, c);
    k_s_partial<<<gS, 256, 0, stream>>>(x, W, c, part);
    k_reduce_squash<<<640, 256, 0, stream>>>(part, v, out);
}

// Round 5
// 155.921 us; speedup vs baseline: 7.0067x; 1.2776x over previous
//
#include <hip/hip_runtime.h>
#include <math.h>

#define B 256
#define N 1152
#define C_ 10
#define OUT 16
#define IN 8
#define KO 160          // C_*OUT
#define MB 32           // batch tile per block (16 thread-groups x BT=2)
#define NC 36           // n-chunk
#define NCH 32          // N / NC
#define KG 2            // capsules per k-group
#define NKG 5
#define NPAIR (NCH*NKG)         // 160 (ch,kg) pairs
#define PAIR_PER_XCD (NPAIR/8)  // 20
#define XS_STRIDE (NC*IN + 8)   // 296 floats; 16B-aligned rows

// ---------------- s-partial: partial[ch][b][k*16+o] = sum_{n in chunk} c[n,k]*(W[n,k,o,:].x[b,n,:])
// 1D grid 1280, XCD-swizzled: g=id%8 (XCD), all 8 b-tiles of a (ch,kg) pair run
// consecutively on ONE XCD -> W chunk (37KB) L2-resident, 20 pairs/XCD = 740KB < 4MB.
__global__ __launch_bounds__(256, 4) void k_s_partial(
    const float* __restrict__ x, const float* __restrict__ W,
    const float* __restrict__ c, float* __restrict__ partial)
{
    __shared__ float xs[MB][XS_STRIDE];   // 32 x 296 x 4B = 37.9 KB
    __shared__ float cs[NC][KG];

    const int tid = threadIdx.x;
    const int id  = blockIdx.x;
    const int g   = id & 7;         // XCD (round-robin dispatch assumption)
    const int q   = id >> 3;        // 0..159 within XCD
    const int bt  = q & 7;          // b-tile fastest within XCD
    const int pp_ = q >> 3;         // 0..19
    const int pair = g * PAIR_PER_XCD + pp_;   // 0..159
    const int ch  = pair & 31;
    const int kg  = pair >> 5;      // 0..4
    const int b0  = bt * MB;
    const int n0  = ch * NC;
    const int k0  = kg * KG;

    // stage x tile: 32 rows x 288 contiguous floats (72 float4 each)
    for (int idx = tid; idx < MB * (NC * IN / 4); idx += 256) {
        int bl = idx / (NC * IN / 4);       // /72
        int r  = idx - bl * (NC * IN / 4);
        float4 val = *(const float4*)(x + (size_t)(b0 + bl) * (N * IN) + (size_t)n0 * IN + r * 4);
        *(float4*)(&xs[bl][r * 4]) = val;
    }
    if (c) {
        for (int idx = tid; idx < NC * KG; idx += 256) {
            int nl = idx >> 1, kk = idx & 1;
            cs[nl][kk] = c[(size_t)(n0 + nl) * C_ + (k0 + kk)];
        }
    }
    __syncthreads();

    const int o    = tid & 15;
    const int bgrp = tid >> 4;      // 0..15; handles rows bgrp and bgrp+16

    float acc00 = 0.f, acc01 = 0.f, acc10 = 0.f, acc11 = 0.f;  // [b(2)][k(2)]

    const float* Wbase = W + (size_t)n0 * (KO * IN) + (size_t)(k0 * OUT + o) * IN;

#pragma unroll 2
    for (int nl = 0; nl < NC; ++nl) {
        float4 xa0 = *(const float4*)(&xs[bgrp][nl * IN]);
        float4 xa1 = *(const float4*)(&xs[bgrp][nl * IN + 4]);
        float4 xb0 = *(const float4*)(&xs[bgrp + 16][nl * IN]);
        float4 xb1 = *(const float4*)(&xs[bgrp + 16][nl * IN + 4]);
        const float* Wn = Wbase + (size_t)nl * (KO * IN);
        float cw0 = c ? cs[nl][0] : 0.1f;
        float cw1 = c ? cs[nl][1] : 0.1f;

        {
            const float4* wp = (const float4*)(Wn);
            float4 w0 = wp[0], w1 = wp[1];
            float da = w0.x*xa0.x + w0.y*xa0.y + w0.z*xa0.z + w0.w*xa0.w
                     + w1.x*xa1.x + w1.y*xa1.y + w1.z*xa1.z + w1.w*xa1.w;
            float db = w0.x*xb0.x + w0.y*xb0.y + w0.z*xb0.z + w0.w*xb0.w
                     + w1.x*xb1.x + w1.y*xb1.y + w1.z*xb1.z + w1.w*xb1.w;
            acc00 += cw0 * da;  acc10 += cw0 * db;
        }
        {
            const float4* wp = (const float4*)(Wn + OUT * IN);
            float4 w0 = wp[0], w1 = wp[1];
            float da = w0.x*xa0.x + w0.y*xa0.y + w0.z*xa0.z + w0.w*xa0.w
                     + w1.x*xa1.x + w1.y*xa1.y + w1.z*xa1.z + w1.w*xa1.w;
            float db = w0.x*xb0.x + w0.y*xb0.y + w0.z*xb0.z + w0.w*xb0.w
                     + w1.x*xb1.x + w1.y*xb1.y + w1.z*xb1.z + w1.w*xb1.w;
            acc01 += cw1 * da;  acc11 += cw1 * db;
        }
    }

    float* ppa = partial + (size_t)ch * (B * KO) + (size_t)(b0 + bgrp) * KO + (size_t)k0 * OUT + o;
    float* ppb = ppa + (size_t)16 * KO;
    ppa[0]   = acc00;  ppa[OUT] = acc01;
    ppb[0]   = acc10;  ppb[OUT] = acc11;
}

// ---------------- reduce partials over chunks + squash; 4 threads per element
// grid 640 blocks x 256: block handles 64 elements
__global__ __launch_bounds__(256) void k_reduce_squash(
    const float* __restrict__ partial, float* __restrict__ v, float* __restrict__ out)
{
    __shared__ float red[256];
    const int tid = threadIdx.x;
    const int e   = blockIdx.x * 64 + (tid >> 2);   // element 0..40959
    const int q   = tid & 3;                        // quarter: 8 chunks each
    float s = 0.f;
#pragma unroll
    for (int ch = 0; ch < NCH / 4; ++ch)
        s += partial[(size_t)(q * (NCH / 4) + ch) * (B * KO) + e];
    red[tid] = s;
    __syncthreads();
    if (q == 0) {
        s = red[tid] + red[tid + 1] + red[tid + 2] + red[tid + 3];
        float vv = s * fabsf(s) / (1.f + s * s);
        v[e] = vv;
        if (out) out[e] = vv;
    }
}

// ---------------- a-pass: b_ij[n][k] (+)= (1/B) sum_{b,o} (W[n,k,o,:].x[b,n,:]) * v[b,k,o]
__global__ __launch_bounds__(256) void k_a(
    const float* __restrict__ x, const float* __restrict__ W,
    const float* __restrict__ v, float* __restrict__ bij, int accumulate)
{
    const int n = blockIdx.x;
    const int tid = threadIdx.x;

    __shared__ float Wl[KO][IN + 1];   // padded: stride 9 -> conflict-free
    __shared__ float xsl[B][IN];       // 8 KB
    __shared__ float red[256][C_];     // 10 KB

    for (int idx = tid; idx < KO * IN; idx += 256)
        Wl[idx >> 3][idx & 7] = W[(size_t)n * (KO * IN) + idx];
    for (int idx = tid; idx < B * IN / 4; idx += 256) {   // 512 float4
        int bb = idx >> 1, r = idx & 1;
        *(float4*)(&xsl[bb][r * 4]) = *(const float4*)(x + (size_t)bb * (N * IN) + (size_t)n * IN + r * 4);
    }
    __syncthreads();

    const int o = tid & 15;
    const int blane = tid >> 4;

    float part[C_];
#pragma unroll
    for (int k = 0; k < C_; ++k) part[k] = 0.f;

    for (int t = 0; t < B / 16; ++t) {
        int bb = blane + t * 16;
        float xv[IN];
#pragma unroll
        for (int i = 0; i < IN; ++i) xv[i] = xsl[bb][i];
        const float* vb = v + (size_t)bb * KO + o;
#pragma unroll
        for (int k = 0; k < C_; ++k) {
            const float* wp = &Wl[k * OUT + o][0];
            float d = 0.f;
#pragma unroll
            for (int i = 0; i < IN; ++i) d += wp[i] * xv[i];
            part[k] += d * vb[k * OUT];
        }
    }

#pragma unroll
    for (int k = 0; k < C_; ++k) red[tid][k] = part[k];
    __syncthreads();
    for (int off = 128; off > 0; off >>= 1) {
        if (tid < off) {
#pragma unroll
            for (int k = 0; k < C_; ++k) red[tid][k] += red[tid + off][k];
        }
        __syncthreads();
    }
    if (tid < C_) {
        float a = red[0][tid] * (1.0f / B);
        float* bp = bij + (size_t)n * C_ + tid;
        *bp = accumulate ? (*bp + a) : a;
    }
}

// ---------------- softmax over k (10) per n
__global__ __launch_bounds__(256) void k_softmax(
    const float* __restrict__ bij, float* __restrict__ c)
{
    int n = blockIdx.x * 256 + threadIdx.x;
    if (n >= N) return;
    float b[C_], m = -1e30f;
#pragma unroll
    for (int k = 0; k < C_; ++k) { b[k] = bij[(size_t)n * C_ + k]; m = fmaxf(m, b[k]); }
    float s = 0.f;
#pragma unroll
    for (int k = 0; k < C_; ++k) { float e = __expf(b[k] - m); b[k] = e; s += e; }
    float inv = 1.f / s;
#pragma unroll
    for (int k = 0; k < C_; ++k) c[(size_t)n * C_ + k] = b[k] * inv;
}

extern "C" void kernel_launch(void* const* d_in, const int* in_sizes, int n_in,
                              void* d_out, int out_size, void* d_ws, size_t ws_size,
                              hipStream_t stream)
{
    const float* x = (const float*)d_in[0];   // [B, N, IN]
    const float* W = (const float*)d_in[1];   // [1, N, C, OUT, IN]
    float* out = (float*)d_out;               // [B, C, OUT, 1] = 40960 floats
    float* ws  = (float*)d_ws;

    float* part = ws;                         // 32 * 40960 = 1310720 floats (5.24 MB)
    float* bij  = ws + 1310720;               // 11520
    float* c    = bij + 11520;                // 11520
    float* v    = c + 11520;                  // 40960

    const int GS = 8 * PAIR_PER_XCD * 8;      // 1280 blocks

    // iteration 0: c = 1/C exactly (softmax of zeros); b_ij = a  (write mode, no init needed)
    k_s_partial<<<GS, 256, 0, stream>>>(x, W, nullptr, part);
    k_reduce_squash<<<640, 256, 0, stream>>>(part, v, nullptr);
    k_a<<<N, 256, 0, stream>>>(x, W, v, bij, 0);

    // iteration 1
    k_softmax<<<5, 256, 0, stream>>>(bij, c);
    k_s_partial<<<GS, 256, 0, stream>>>(x, W, c, part);
    k_reduce_squash<<<640, 256, 0, stream>>>(part, v, nullptr);
    k_a<<<N, 256, 0, stream>>>(x, W, v, bij, 1);

    // iteration 2 (final: write d_out)
    k_softmax<<<5, 256, 0, stream>>>(bij, c);
    k_s_partial<<<GS, 256, 0, stream>>>(x, W, c, part);
    k_reduce_squash<<<640, 256, 0, stream>>>(part, v, out);
}

// Round 6
// 147.541 us; speedup vs baseline: 7.4047x; 1.0568x over previous
//
#include <hip/hip_runtime.h>
#include <math.h>

#define B 256
#define N 1152
#define C_ 10
#define OUT 16
#define IN 8
#define KO 160          // C_*OUT
#define MB 32           // batch rows per block (16 thread-groups x BT=2)
#define NC 18           // n-chunk
#define NCH 64          // N / NC
#define KG 2            // capsules per k-group
#define NKG 5
#define NPAIR (NCH*NKG)         // 320 (ch,kg) pairs
#define PAIR_PER_XCD (NPAIR/8)  // 40
#define XS_STRIDE (NC*IN + 8)   // 152 floats; rows 608B apart (16B-aligned, banks spread)

// ---------------- s-partial: partial[ch][b][k*16+o] = sum_{n in chunk} c[n,k]*(W[n,k,o,:].x[b,n,:])
// 1D grid 2560. XCD swizzle: g=id&7. Within an XCD, kg fastest (5 kg share one x-slice),
// then ch (8 per XCD): per-XCD working set = 8*(92KB W + 147KB x) = 1.9MB -> L2-resident.
// LDS 19.5KB -> 8 blocks/CU resident (32 waves). Manual W prefetch pipeline (R5: VALUBusy
// was 28% -- compiler wasn't hiding W-load latency).
__global__ __launch_bounds__(256, 4) void k_s_partial(
    const float* __restrict__ x, const float* __restrict__ W,
    const float* __restrict__ c, float* __restrict__ partial)
{
    __shared__ float xs[MB][XS_STRIDE];   // 32 x 152 x 4B = 19.5 KB
    __shared__ float cs[NC][KG];

    const int tid = threadIdx.x;
    const int id  = blockIdx.x;
    const int g   = id & 7;         // XCD
    const int q   = id >> 3;        // 0..319 within XCD
    const int bt  = q & 7;          // b-tile fastest
    const int pp_ = q >> 3;         // 0..39
    const int kg  = pp_ % 5;        // kg fastest among pairs -> x reuse within XCD
    const int ch  = g * (PAIR_PER_XCD / 5) + pp_ / 5;   // 0..63
    const int b0  = bt * MB;
    const int n0  = ch * NC;
    const int k0  = kg * KG;

    // stage x tile: 32 rows x 144 contiguous floats (36 float4 each)
    for (int idx = tid; idx < MB * (NC * IN / 4); idx += 256) {
        int bl = idx / (NC * IN / 4);       // /36
        int r  = idx - bl * (NC * IN / 4);
        float4 val = *(const float4*)(x + (size_t)(b0 + bl) * (N * IN) + (size_t)n0 * IN + r * 4);
        *(float4*)(&xs[bl][r * 4]) = val;
    }
    if (c) {
        for (int idx = tid; idx < NC * KG; idx += 256) {
            int nl = idx >> 1, kk = idx & 1;
            cs[nl][kk] = c[(size_t)(n0 + nl) * C_ + (k0 + kk)];
        }
    }
    __syncthreads();

    const int o    = tid & 15;
    const int bgrp = tid >> 4;      // 0..15; rows bgrp and bgrp+16

    float acc00 = 0.f, acc01 = 0.f, acc10 = 0.f, acc11 = 0.f;  // [b(2)][k(2)]

    const float* Wbase = W + (size_t)n0 * (KO * IN) + (size_t)(k0 * OUT + o) * IN;

    // prefetch nl=0
    float4 w00 = *(const float4*)(Wbase);
    float4 w01 = *(const float4*)(Wbase + 4);
    float4 w10 = *(const float4*)(Wbase + OUT * IN);
    float4 w11 = *(const float4*)(Wbase + OUT * IN + 4);

#pragma unroll 2
    for (int nl = 0; nl < NC; ++nl) {
        // issue next-iteration W loads first (rotate at loop end)
        const int nn = (nl + 1 < NC) ? (nl + 1) : nl;
        const float* Wn = Wbase + (size_t)nn * (KO * IN);
        float4 p00 = *(const float4*)(Wn);
        float4 p01 = *(const float4*)(Wn + 4);
        float4 p10 = *(const float4*)(Wn + OUT * IN);
        float4 p11 = *(const float4*)(Wn + OUT * IN + 4);

        float4 xa0 = *(const float4*)(&xs[bgrp][nl * IN]);
        float4 xa1 = *(const float4*)(&xs[bgrp][nl * IN + 4]);
        float4 xb0 = *(const float4*)(&xs[bgrp + 16][nl * IN]);
        float4 xb1 = *(const float4*)(&xs[bgrp + 16][nl * IN + 4]);
        float cw0 = c ? cs[nl][0] : 0.1f;
        float cw1 = c ? cs[nl][1] : 0.1f;

        float da0 = w00.x*xa0.x + w00.y*xa0.y + w00.z*xa0.z + w00.w*xa0.w
                  + w01.x*xa1.x + w01.y*xa1.y + w01.z*xa1.z + w01.w*xa1.w;
        float db0 = w00.x*xb0.x + w00.y*xb0.y + w00.z*xb0.z + w00.w*xb0.w
                  + w01.x*xb1.x + w01.y*xb1.y + w01.z*xb1.z + w01.w*xb1.w;
        float da1 = w10.x*xa0.x + w10.y*xa0.y + w10.z*xa0.z + w10.w*xa0.w
                  + w11.x*xa1.x + w11.y*xa1.y + w11.z*xa1.z + w11.w*xa1.w;
        float db1 = w10.x*xb0.x + w10.y*xb0.y + w10.z*xb0.z + w10.w*xb0.w
                  + w11.x*xb1.x + w11.y*xb1.y + w11.z*xb1.z + w11.w*xb1.w;

        acc00 += cw0 * da0;  acc10 += cw0 * db0;
        acc01 += cw1 * da1;  acc11 += cw1 * db1;

        w00 = p00; w01 = p01; w10 = p10; w11 = p11;
    }

    float* ppa = partial + (size_t)ch * (B * KO) + (size_t)(b0 + bgrp) * KO + (size_t)k0 * OUT + o;
    float* ppb = ppa + (size_t)16 * KO;
    ppa[0]   = acc00;  ppa[OUT] = acc01;
    ppb[0]   = acc10;  ppb[OUT] = acc11;
}

// ---------------- reduce partials over 64 chunks + squash; 4 threads per element
// grid 640 blocks x 256: block handles 64 elements
__global__ __launch_bounds__(256) void k_reduce_squash(
    const float* __restrict__ partial, float* __restrict__ v, float* __restrict__ out)
{
    __shared__ float red[256];
    const int tid = threadIdx.x;
    const int e   = blockIdx.x * 64 + (tid >> 2);   // element 0..40959
    const int q   = tid & 3;                        // quarter: 16 chunks each
    float s = 0.f;
#pragma unroll
    for (int ch = 0; ch < NCH / 4; ++ch)
        s += partial[(size_t)(q * (NCH / 4) + ch) * (B * KO) + e];
    red[tid] = s;
    __syncthreads();
    if (q == 0) {
        s = red[tid] + red[tid + 1] + red[tid + 2] + red[tid + 3];
        float vv = s * fabsf(s) / (1.f + s * s);
        v[e] = vv;
        if (out) out[e] = vv;
    }
}

// ---------------- a-pass: b_ij[n][k] (+)= (1/B) sum_{b,o} (W[n,k,o,:].x[b,n,:]) * v[b,k,o]
__global__ __launch_bounds__(256) void k_a(
    const float* __restrict__ x, const float* __restrict__ W,
    const float* __restrict__ v, float* __restrict__ bij, int accumulate)
{
    const int n = blockIdx.x;
    const int tid = threadIdx.x;

    __shared__ float Wl[KO][IN + 1];   // padded: stride 9 -> conflict-free
    __shared__ float xsl[B][IN];       // 8 KB
    __shared__ float red[256][C_];     // 10 KB

    for (int idx = tid; idx < KO * IN; idx += 256)
        Wl[idx >> 3][idx & 7] = W[(size_t)n * (KO * IN) + idx];
    for (int idx = tid; idx < B * IN / 4; idx += 256) {   // 512 float4
        int bb = idx >> 1, r = idx & 1;
        *(float4*)(&xsl[bb][r * 4]) = *(const float4*)(x + (size_t)bb * (N * IN) + (size_t)n * IN + r * 4);
    }
    __syncthreads();

    const int o = tid & 15;
    const int blane = tid >> 4;

    float part[C_];
#pragma unroll
    for (int k = 0; k < C_; ++k) part[k] = 0.f;

    for (int t = 0; t < B / 16; ++t) {
        int bb = blane + t * 16;
        float xv[IN];
#pragma unroll
        for (int i = 0; i < IN; ++i) xv[i] = xsl[bb][i];
        const float* vb = v + (size_t)bb * KO + o;
#pragma unroll
        for (int k = 0; k < C_; ++k) {
            const float* wp = &Wl[k * OUT + o][0];
            float d = 0.f;
#pragma unroll
            for (int i = 0; i < IN; ++i) d += wp[i] * xv[i];
            part[k] += d * vb[k * OUT];
        }
    }

#pragma unroll
    for (int k = 0; k < C_; ++k) red[tid][k] = part[k];
    __syncthreads();
    for (int off = 128; off > 0; off >>= 1) {
        if (tid < off) {
#pragma unroll
            for (int k = 0; k < C_; ++k) red[tid][k] += red[tid + off][k];
        }
        __syncthreads();
    }
    if (tid < C_) {
        float a = red[0][tid] * (1.0f / B);
        float* bp = bij + (size_t)n * C_ + tid;
        *bp = accumulate ? (*bp + a) : a;
    }
}

// ---------------- softmax over k (10) per n
__global__ __launch_bounds__(256) void k_softmax(
    const float* __restrict__ bij, float* __restrict__ c)
{
    int n = blockIdx.x * 256 + threadIdx.x;
    if (n >= N) return;
    float b[C_], m = -1e30f;
#pragma unroll
    for (int k = 0; k < C_; ++k) { b[k] = bij[(size_t)n * C_ + k]; m = fmaxf(m, b[k]); }
    float s = 0.f;
#pragma unroll
    for (int k = 0; k < C_; ++k) { float e = __expf(b[k] - m); b[k] = e; s += e; }
    float inv = 1.f / s;
#pragma unroll
    for (int k = 0; k < C_; ++k) c[(size_t)n * C_ + k] = b[k] * inv;
}

extern "C" void kernel_launch(void* const* d_in, const int* in_sizes, int n_in,
                              void* d_out, int out_size, void* d_ws, size_t ws_size,
                              hipStream_t stream)
{
    const float* x = (const float*)d_in[0];   // [B, N, IN]
    const float* W = (const float*)d_in[1];   // [1, N, C, OUT, IN]
    float* out = (float*)d_out;               // [B, C, OUT, 1] = 40960 floats
    float* ws  = (float*)d_ws;

    float* part = ws;                         // 64 * 40960 = 2621440 floats (10.5 MB)
    float* bij  = ws + 2621440;               // 11520
    float* c    = bij + 11520;                // 11520
    float* v    = c + 11520;                  // 40960

    const int GS = 8 * PAIR_PER_XCD * 8;      // 2560 blocks

    // iteration 0: c = 1/C exactly (softmax of zeros); b_ij = a  (write mode, no init needed)
    k_s_partial<<<GS, 256, 0, stream>>>(x, W, nullptr, part);
    k_reduce_squash<<<640, 256, 0, stream>>>(part, v, nullptr);
    k_a<<<N, 256, 0, stream>>>(x, W, v, bij, 0);

    // iteration 1
    k_softmax<<<5, 256, 0, stream>>>(bij, c);
    k_s_partial<<<GS, 256, 0, stream>>>(x, W, c, part);
    k_reduce_squash<<<640, 256, 0, stream>>>(part, v, nullptr);
    k_a<<<N, 256, 0, stream>>>(x, W, v, bij, 1);

    // iteration 2 (final: write d_out)
    k_softmax<<<5, 256, 0, stream>>>(bij, c);
    k_s_partial<<<GS, 256, 0, stream>>>(x, W, c, part);
    k_reduce_squash<<<640, 256, 0, stream>>>(part, v, out);
}